// Round 15
// baseline (218.280 us; speedup 1.0000x reference)
//
#include <hip/hip_runtime.h>
#include <math.h>

#define HID 128
#define TT 32

typedef __attribute__((ext_vector_type(8))) short short8v;   // 8 bf16 = 4 VGPRs
typedef __attribute__((ext_vector_type(16))) float f32x16;   // MFMA 32x32 acc

// ---------- DPP wave64 sum (verified R1-R14) ----------
template<int CTRL, int RMASK>
__device__ __forceinline__ float dpp_add_stage(float v) {
  int s = __builtin_amdgcn_update_dpp(0, __float_as_int(v), CTRL, RMASK, 0xf, true);
  return v + __int_as_float(s);
}
__device__ __forceinline__ float wave_red_sum(float v) {
  v = dpp_add_stage<0x111, 0xf>(v);
  v = dpp_add_stage<0x112, 0xf>(v);
  v = dpp_add_stage<0x114, 0xf>(v);
  v = dpp_add_stage<0x118, 0xf>(v);
  v = dpp_add_stage<0x142, 0xa>(v);
  v = dpp_add_stage<0x143, 0xc>(v);
  return __int_as_float(__builtin_amdgcn_readlane(__float_as_int(v), 63));
}

#define REP8(F) F(0) F(1) F(2) F(3) F(4) F(5) F(6) F(7)

// Encode one 32-step tile into bf16 hi/lo LDS buffers (4-bit-XOR swizzled).
// Pre-scaled u = s*x - s*th (literals) + __expf(-u*u) -> fast v_exp_f32 path.
// Trunc-split hi + RN residual lo (verified r10-r14). tid2 = (t<<2) | channel.
__device__ __forceinline__ void encode_tile(
    int tid2, int tile, unsigned int* Eh, unsigned int* El,
    const float* __restrict__ xb) {
  const int t5 = tid2 >> 2;       // 0..31 (t within tile)
  const int ch = tid2 & 3;        // channel
  const double S_D = 4.525483399593904156;   // sqrt(512/25)
  const float  S_F = (float)S_D;
  float xc = xb[(tile * TT + t5) * 4 + ch];
#pragma unroll
  for (int c2 = 0; c2 < 4; ++c2) {          // 4 chunks of 8 thresholds
    unsigned int hi4[4], lo4[4];
#pragma unroll
    for (int p = 0; p < 4; ++p) {           // pairs within chunk
      int j0 = c2 * 8 + p * 2;
      float a0 = (float)(S_D * ((double)j0 * (6.0 / 31.0) - 3.0));
      float a1 = (float)(S_D * ((double)(j0 + 1) * (6.0 / 31.0) - 3.0));
      float u0f = fmaf(xc, S_F, -a0);
      float u1f = fmaf(xc, S_F, -a1);
      float e0 = __expf(-(u0f * u0f));
      float e1 = __expf(-(u1f * u1f));
      unsigned u0 = __float_as_uint(e0);
      unsigned u1 = __float_as_uint(e1);
      hi4[p] = __builtin_amdgcn_perm(u1, u0, 0x07060302u);   // trunc-bf16 pair
      float l0 = e0 - __uint_as_float(u0 & 0xffff0000u);
      float l1 = e1 - __uint_as_float(u1 & 0xffff0000u);
      unsigned v0 = __float_as_uint(l0) + 0x8000u;           // RN-bf16 residual
      unsigned v1 = __float_as_uint(l1) + 0x8000u;
      lo4[p] = __builtin_amdgcn_perm(v1, v0, 0x07060302u);
    }
    int chunk = ch * 4 + c2;
    int idx = t5 * 64 + (((chunk ^ t5) & 15) << 2);  // 4-bit XOR swizzle
    *(uint4*)&Eh[idx] = make_uint4(hi4[0], hi4[1], hi4[2], hi4[3]);
    *(uint4*)&El[idx] = make_uint4(lo4[0], lo4[1], lo4[2], lo4[3]);
  }
}

// 4 waves / block, 1 batch element / block. Wave w owns output rows 32w..32w+31.
// r12's zero-spill 3-phase skeleton, now at 4 blocks/CU:
// [RDB + 24 MFMA (2 chains) + extract] B1 [LN finish + Hn2 write] B2
// [scan(W01) | encode(next, W23)] B3.
// waves_per_eu(4,4): reg cap 128 >= measured demand 84 (r12: zero spill at 84);
// LDS 34304 B x 4 blocks = 137 KB <= 160 KB -> 4 blocks/CU, +33% TLP to cover
// the ~34% latency-stall fraction measured in r12/r14.
__global__ __launch_bounds__(256) __attribute__((amdgpu_waves_per_eu(4, 4)))
void snn_mfma_kernel(
    const float* __restrict__ x, const float* __restrict__ Win,
    const float* __restrict__ b_in, const float* __restrict__ ln_g,
    const float* __restrict__ ln_b, const float* __restrict__ Wout,
    const float* __restrict__ b_out, float* __restrict__ out, int T) {
  __shared__ unsigned int Ebuf[2][TT * 64];     // 16 KB [hi/lo] bf16x2, swizzled
  __shared__ float2 Hn2[TT / 2][HID];           // 16 KB paired (h-mu)*rstd
  __shared__ float red[256];                    // 1 KB  LN partials / epilogue
  __shared__ float bias_lds[HID];               // 0.5 KB b_in broadcast table

  const int tid = threadIdx.x;
  const int w   = tid >> 6;        // wave 0..3 = M-tile
  const int l   = tid & 63;
  const int hh  = l >> 5;          // lane half -> k-subchunk
  const int l31 = l & 31;          // A row / B col (=t) within tile
  const int b   = blockIdx.x;
  const int ntiles = T / TT;
  const float* xb = x + (size_t)b * (size_t)T * 4;

  // ---- A fragments: W rows 32w+l31, k = kt*16 + hh*8 + j ; bf16 hi/lo ----
  const float* wrow = Win + (size_t)(32 * w + l31) * HID + hh * 8;
#define LDW(kt) short8v wh##kt, wl##kt; { \
    float tmp[8]; \
    *(float4*)&tmp[0] = *(const float4*)(wrow + (kt) * 16); \
    *(float4*)&tmp[4] = *(const float4*)(wrow + (kt) * 16 + 4); \
    _Pragma("unroll") \
    for (int e = 0; e < 8; ++e) { \
      unsigned u = __float_as_uint(tmp[e]) + 0x8000u; \
      wh##kt[e] = (short)(u >> 16); \
      float lof = tmp[e] - __uint_as_float(u & 0xffff0000u); \
      wl##kt[e] = (short)((__float_as_uint(lof) + 0x8000u) >> 16); \
    } }
  REP8(LDW)
#undef LDW

  // scan-phase constants (threads 0..127; masked index keeps loads valid)
  const int srow = tid & 127;
  const float gr10 = 0.1f * ln_g[srow];
  const float br10 = 0.1f * ln_b[srow];
  const float wo0x2 = 2.0f * Wout[srow];
  const float wo1x2 = 2.0f * Wout[HID + srow];
  float mem = 0.f, cnt = 0.f;      // cnt counts spikes in units of 0.5

  auto do_scan = [&]() {
#pragma unroll
    for (int tt2 = 0; tt2 < TT / 2; ++tt2) {
      float2 hn2 = Hn2[tt2][srow ^ tt2];
      float cc0 = fmaf(hn2.x, gr10, br10);
      mem = fmaf(mem, 0.9f, cc0);
      float d0 = (mem > 0.5f) ? 0.5f : 0.0f;
      mem -= d0; cnt += d0;
      float cc1 = fmaf(hn2.y, gr10, br10);
      mem = fmaf(mem, 0.9f, cc1);
      float d1 = (mem > 0.5f) ? 0.5f : 0.0f;
      mem -= d1; cnt += d1;
    }
  };

  if (tid < 128) bias_lds[tid] = b_in[tid];
  else           encode_tile(tid - 128, 0, &Ebuf[0][0], &Ebuf[1][0], xb);
  __syncthreads();

  const unsigned int* Eh = &Ebuf[0][0];
  const unsigned int* El = &Ebuf[1][0];
  const int t5 = l31;              // this lane's output column (=t)
  const int tp = t5 >> 1, par = t5 & 1;

  for (int tau = 0; tau < ntiles; ++tau) {
    // ---- RDB + 24 MFMAs, 2 chains: accA = wh*bh ; accB = wh*bl + wl*bh ----
    f32x16 accA = {}, accB = {};
#define MM(kt) { \
    short8v bh = *(const short8v*)&Eh[t5 * 64 + ((((2 * (kt) + hh) ^ t5) & 15) << 2)]; \
    short8v bl = *(const short8v*)&El[t5 * 64 + ((((2 * (kt) + hh) ^ t5) & 15) << 2)]; \
    accA = __builtin_amdgcn_mfma_f32_32x32x16_bf16(wh##kt, bh, accA, 0, 0, 0); \
    accB = __builtin_amdgcn_mfma_f32_32x32x16_bf16(wh##kt, bl, accB, 0, 0, 0); \
    accB = __builtin_amdgcn_mfma_f32_32x32x16_bf16(wl##kt, bh, accB, 0, 0, 0); }
    REP8(MM)
#undef MM

    // ---- bias (LDS broadcast, transient) + h into accA + LN partials ----
    float bb[16];
    const int rb = 32 * w + 4 * hh;
    *(float4*)&bb[0]  = *(const float4*)&bias_lds[rb];
    *(float4*)&bb[4]  = *(const float4*)&bias_lds[rb + 8];
    *(float4*)&bb[8]  = *(const float4*)&bias_lds[rb + 16];
    *(float4*)&bb[12] = *(const float4*)&bias_lds[rb + 24];
    float s1 = 0.f, s2 = 0.f;
#pragma unroll
    for (int r = 0; r < 16; ++r) {
      float hrv = (accA[r] + accB[r]) + bb[r];
      accA[r] = hrv;                       // hv lives in accA
      s1 += hrv;
      s2 = fmaf(hrv, hrv, s2);
    }
    s1 += __shfl_xor(s1, 32);      // combine lane halves (rows +4*hh)
    s2 += __shfl_xor(s2, 32);
    if (l < 32) *(float2*)&red[w * 64 + 2 * l31] = make_float2(s1, s2);
    __syncthreads();               // B1: partials visible

    float2 q0 = *(const float2*)&red[0 + 2 * l31];
    float2 q1 = *(const float2*)&red[64 + 2 * l31];
    float2 q2 = *(const float2*)&red[128 + 2 * l31];
    float2 q3 = *(const float2*)&red[192 + 2 * l31];
    float S1 = (q0.x + q1.x) + (q2.x + q3.x);
    float S2 = (q0.y + q1.y) + (q2.y + q3.y);
    float mu = S1 * (1.0f / 128.0f);
    float var = S2 * (1.0f / 128.0f) - mu * mu;
    float rstd = 1.0f / sqrtf(var + 1e-5f);
    float sh = -mu * rstd;

    // ---- write (h-mu)*rstd to Hn2 (paired, row^tp swizzle) ----
#pragma unroll
    for (int r = 0; r < 16; ++r) {
      int row = rb + (r & 3) + 8 * (r >> 2);
      ((float*)&Hn2[tp][row ^ tp])[par] = fmaf(accA[r], rstd, sh);
    }
    __syncthreads();               // B2: Hn2 ready

    if (tid < 128) {
      do_scan();                   // scan this tile (membrane + spike count)
    } else if (tau + 1 < ntiles) {
      encode_tile(tid - 128, tau + 1, &Ebuf[0][0], &Ebuf[1][0], xb);
    }
    __syncthreads();               // B3: scan done, E(next) ready
  }

  // ---- epilogue: readout = (2*cnt) spikes * Wout, reduced across rows ----
  float r0 = wave_red_sum(cnt * wo0x2);
  float r1 = wave_red_sum(cnt * wo1x2);
  if ((tid & 63) == 0) { red[w * 64] = r0; red[w * 64 + 1] = r1; }
  __syncthreads();
  if (tid == 0) {
    float R0 = (red[0] + red[64]) + (red[128] + red[192]);
    float R1 = (red[1] + red[65]) + (red[129] + red[193]);
    out[2 * b]     = R0 + (float)T * b_out[0];
    out[2 * b + 1] = R1 + (float)T * b_out[1];
  }
}

extern "C" void kernel_launch(void* const* d_in, const int* in_sizes, int n_in,
                              void* d_out, int out_size, void* d_ws, size_t ws_size,
                              hipStream_t stream) {
  const float* x    = (const float*)d_in[0];
  const float* Win  = (const float*)d_in[1];
  const float* bin  = (const float*)d_in[2];
  const float* lng  = (const float*)d_in[3];
  const float* lnb  = (const float*)d_in[4];
  const float* Wout = (const float*)d_in[5];
  const float* bout = (const float*)d_in[6];
  float* out = (float*)d_out;

  int B = out_size / 2;                 // 2048
  int T = in_sizes[0] / (B * 4);        // 512

  snn_mfma_kernel<<<dim3(B), dim3(256), 0, stream>>>(
      x, Win, bin, lng, lnb, Wout, bout, out, T);
}

// Round 17
// 141.062 us; speedup vs baseline: 1.5474x; 1.5474x over previous
//
#include <hip/hip_runtime.h>
#include <math.h>

#define HID 128
#define TT 32

typedef __attribute__((ext_vector_type(8))) short short8v;   // 8 bf16 = 4 VGPRs
typedef __attribute__((ext_vector_type(16))) float f32x16;   // MFMA 32x32 acc

// ---------- DPP wave64 sum (verified R1-R15) ----------
template<int CTRL, int RMASK>
__device__ __forceinline__ float dpp_add_stage(float v) {
  int s = __builtin_amdgcn_update_dpp(0, __float_as_int(v), CTRL, RMASK, 0xf, true);
  return v + __int_as_float(s);
}
__device__ __forceinline__ float wave_red_sum(float v) {
  v = dpp_add_stage<0x111, 0xf>(v);
  v = dpp_add_stage<0x112, 0xf>(v);
  v = dpp_add_stage<0x114, 0xf>(v);
  v = dpp_add_stage<0x118, 0xf>(v);
  v = dpp_add_stage<0x142, 0xa>(v);
  v = dpp_add_stage<0x143, 0xc>(v);
  return __int_as_float(__builtin_amdgcn_readlane(__float_as_int(v), 63));
}

#define REP8(F) F(0) F(1) F(2) F(3) F(4) F(5) F(6) F(7)

// Encode one 32-step tile into bf16 hi/lo LDS buffers (4-bit-XOR swizzled).
// Pre-scaled u = s*x - s*th (literals) + __expf(-u*u) -> fast v_exp_f32 path.
// Trunc-split hi + RN residual lo (verified r10-r14; r16's cvt_pk variant
// FAILED numerics — instruction half-placement differs from model, reverted).
__device__ __forceinline__ void encode_tile(
    int tid2, int tile, unsigned int* Eh, unsigned int* El,
    const float* __restrict__ xb) {
  const int t5 = tid2 >> 2;       // 0..31 (t within tile)
  const int ch = tid2 & 3;        // channel
  const double S_D = 4.525483399593904156;   // sqrt(512/25)
  const float  S_F = (float)S_D;
  float xc = xb[(tile * TT + t5) * 4 + ch];
#pragma unroll
  for (int c2 = 0; c2 < 4; ++c2) {          // 4 chunks of 8 thresholds
    unsigned int hi4[4], lo4[4];
#pragma unroll
    for (int p = 0; p < 4; ++p) {           // pairs within chunk
      int j0 = c2 * 8 + p * 2;
      float a0 = (float)(S_D * ((double)j0 * (6.0 / 31.0) - 3.0));
      float a1 = (float)(S_D * ((double)(j0 + 1) * (6.0 / 31.0) - 3.0));
      float u0f = fmaf(xc, S_F, -a0);
      float u1f = fmaf(xc, S_F, -a1);
      float e0 = __expf(-(u0f * u0f));
      float e1 = __expf(-(u1f * u1f));
      unsigned u0 = __float_as_uint(e0);
      unsigned u1 = __float_as_uint(e1);
      hi4[p] = __builtin_amdgcn_perm(u1, u0, 0x07060302u);   // trunc-bf16 pair
      float l0 = e0 - __uint_as_float(u0 & 0xffff0000u);
      float l1 = e1 - __uint_as_float(u1 & 0xffff0000u);
      unsigned v0 = __float_as_uint(l0) + 0x8000u;           // RN-bf16 residual
      unsigned v1 = __float_as_uint(l1) + 0x8000u;
      lo4[p] = __builtin_amdgcn_perm(v1, v0, 0x07060302u);
    }
    int chunk = ch * 4 + c2;
    int idx = t5 * 64 + (((chunk ^ t5) & 15) << 2);  // 4-bit XOR swizzle
    *(uint4*)&Eh[idx] = make_uint4(hi4[0], hi4[1], hi4[2], hi4[3]);
    *(uint4*)&El[idx] = make_uint4(lo4[0], lo4[1], lo4[2], lo4[3]);
  }
}

// 4 waves / block, 1 batch element / block. Wave w owns output rows 32w..32w+31.
// Champion structure (r14, 141.2 us): TWO barriers/tile via Hn2 double-buffer:
// P1 [RDB(E) + 24 MFMA (2 chains) + extract + LN partials] B1
// P2 [LN finish + Hn2[p] write; scan(tau-1) from Hn2[p^1] (W01) ∥
//     encode(tau+1) -> E (W23)] B2.
// waves_per_eu(3,3): the proven zero-spill occupancy (r15: 4 waves/EU spills —
// true unified demand ~= 84 arch + 32 acc > 128 cap).
__global__ __launch_bounds__(256) __attribute__((amdgpu_waves_per_eu(3, 3)))
void snn_mfma_kernel(
    const float* __restrict__ x, const float* __restrict__ Win,
    const float* __restrict__ b_in, const float* __restrict__ ln_g,
    const float* __restrict__ ln_b, const float* __restrict__ Wout,
    const float* __restrict__ b_out, float* __restrict__ out, int T) {
  __shared__ unsigned int Ebuf[2][TT * 64];     // 16 KB [hi/lo] bf16x2, swizzled
  __shared__ float2 Hn2[2][TT / 2][HID];        // 32 KB dbuf paired (h-mu)*rstd
  __shared__ float red[256];                    // 1 KB  LN partials / epilogue
  __shared__ float bias_lds[HID];               // 0.5 KB b_in broadcast table

  const int tid = threadIdx.x;
  const int w   = tid >> 6;        // wave 0..3 = M-tile
  const int l   = tid & 63;
  const int hh  = l >> 5;          // lane half -> k-subchunk
  const int l31 = l & 31;          // A row / B col (=t) within tile
  const int b   = blockIdx.x;
  const int ntiles = T / TT;
  const float* xb = x + (size_t)b * (size_t)T * 4;

  // ---- A fragments: W rows 32w+l31, k = kt*16 + hh*8 + j ; bf16 hi/lo ----
  const float* wrow = Win + (size_t)(32 * w + l31) * HID + hh * 8;
#define LDW(kt) short8v wh##kt, wl##kt; { \
    float tmp[8]; \
    *(float4*)&tmp[0] = *(const float4*)(wrow + (kt) * 16); \
    *(float4*)&tmp[4] = *(const float4*)(wrow + (kt) * 16 + 4); \
    _Pragma("unroll") \
    for (int e = 0; e < 8; ++e) { \
      unsigned u = __float_as_uint(tmp[e]) + 0x8000u; \
      wh##kt[e] = (short)(u >> 16); \
      float lof = tmp[e] - __uint_as_float(u & 0xffff0000u); \
      wl##kt[e] = (short)((__float_as_uint(lof) + 0x8000u) >> 16); \
    } }
  REP8(LDW)
#undef LDW

  // scan-phase constants (threads 0..127; masked index keeps loads valid)
  const int srow = tid & 127;
  const float gr10 = 0.1f * ln_g[srow];
  const float br10 = 0.1f * ln_b[srow];
  const float wo0x2 = 2.0f * Wout[srow];
  const float wo1x2 = 2.0f * Wout[HID + srow];
  float mem = 0.f, cnt = 0.f;      // cnt counts spikes in units of 0.5

  auto do_scan = [&](const float2 (*H)[HID]) {
#pragma unroll
    for (int tt2 = 0; tt2 < TT / 2; ++tt2) {
      float2 hn2 = H[tt2][srow ^ tt2];
      float cc0 = fmaf(hn2.x, gr10, br10);
      mem = fmaf(mem, 0.9f, cc0);
      float d0 = (mem > 0.5f) ? 0.5f : 0.0f;
      mem -= d0; cnt += d0;
      float cc1 = fmaf(hn2.y, gr10, br10);
      mem = fmaf(mem, 0.9f, cc1);
      float d1 = (mem > 0.5f) ? 0.5f : 0.0f;
      mem -= d1; cnt += d1;
    }
  };

  if (tid < 128) bias_lds[tid] = b_in[tid];
  else           encode_tile(tid - 128, 0, &Ebuf[0][0], &Ebuf[1][0], xb);
  __syncthreads();

  const unsigned int* Eh = &Ebuf[0][0];
  const unsigned int* El = &Ebuf[1][0];
  const int t5 = l31;              // this lane's output column (=t)
  const int tp = t5 >> 1, par = t5 & 1;

  for (int tau = 0; tau < ntiles; ++tau) {
    const int p = tau & 1;

    // ---- P1: RDB + 24 MFMAs, 2 chains: accA = wh*bh ; accB = wh*bl+wl*bh ----
    f32x16 accA = {}, accB = {};
#define MM(kt) { \
    short8v bh = *(const short8v*)&Eh[t5 * 64 + ((((2 * (kt) + hh) ^ t5) & 15) << 2)]; \
    short8v bl = *(const short8v*)&El[t5 * 64 + ((((2 * (kt) + hh) ^ t5) & 15) << 2)]; \
    accA = __builtin_amdgcn_mfma_f32_32x32x16_bf16(wh##kt, bh, accA, 0, 0, 0); \
    accB = __builtin_amdgcn_mfma_f32_32x32x16_bf16(wh##kt, bl, accB, 0, 0, 0); \
    accB = __builtin_amdgcn_mfma_f32_32x32x16_bf16(wl##kt, bh, accB, 0, 0, 0); }
    REP8(MM)
#undef MM

    // ---- bias (LDS broadcast, transient) + h into accA + LN partials ----
    float bb[16];
    const int rb = 32 * w + 4 * hh;
    *(float4*)&bb[0]  = *(const float4*)&bias_lds[rb];
    *(float4*)&bb[4]  = *(const float4*)&bias_lds[rb + 8];
    *(float4*)&bb[8]  = *(const float4*)&bias_lds[rb + 16];
    *(float4*)&bb[12] = *(const float4*)&bias_lds[rb + 24];
    float s1 = 0.f, s2 = 0.f;
#pragma unroll
    for (int r = 0; r < 16; ++r) {
      float hrv = (accA[r] + accB[r]) + bb[r];
      accA[r] = hrv;                       // hv lives in accA
      s1 += hrv;
      s2 = fmaf(hrv, hrv, s2);
    }
    s1 += __shfl_xor(s1, 32);      // combine lane halves (rows +4*hh)
    s2 += __shfl_xor(s2, 32);
    if (l < 32) *(float2*)&red[w * 64 + 2 * l31] = make_float2(s1, s2);
    __syncthreads();               // B1: partials visible; RDB(E) reads done

    // ---- P2: LN finish + Hn2[p] write ----
    float2 q0 = *(const float2*)&red[0 + 2 * l31];
    float2 q1 = *(const float2*)&red[64 + 2 * l31];
    float2 q2 = *(const float2*)&red[128 + 2 * l31];
    float2 q3 = *(const float2*)&red[192 + 2 * l31];
    float S1 = (q0.x + q1.x) + (q2.x + q3.x);
    float S2 = (q0.y + q1.y) + (q2.y + q3.y);
    float mu = S1 * (1.0f / 128.0f);
    float var = S2 * (1.0f / 128.0f) - mu * mu;
    float rstd = 1.0f / sqrtf(var + 1e-5f);
    float sh = -mu * rstd;
#pragma unroll
    for (int r = 0; r < 16; ++r) {
      int row = rb + (r & 3) + 8 * (r >> 2);
      ((float*)&Hn2[p][tp][row ^ tp])[par] = fmaf(accA[r], rstd, sh);
    }

    // ---- P2 overlap: scan(tau-1) on W01 ∥ encode(tau+1) on W23 ----
    if (tid < 128) {
      if (tau > 0) do_scan(Hn2[p ^ 1]);
    } else if (tau + 1 < ntiles) {
      encode_tile(tid - 128, tau + 1, &Ebuf[0][0], &Ebuf[1][0], xb);
    }
    __syncthreads();               // B2: Hn2[p] sealed; E(next) ready
  }

  // ---- epilogue: scan the last tile, then readout reduction ----
  if (tid < 128) do_scan(Hn2[(ntiles - 1) & 1]);
  float r0 = wave_red_sum(cnt * wo0x2);
  float r1 = wave_red_sum(cnt * wo1x2);
  if ((tid & 63) == 0) { red[w * 64] = r0; red[w * 64 + 1] = r1; }
  __syncthreads();
  if (tid == 0) {
    float R0 = (red[0] + red[64]) + (red[128] + red[192]);
    float R1 = (red[1] + red[65]) + (red[129] + red[193]);
    out[2 * b]     = R0 + (float)T * b_out[0];
    out[2 * b + 1] = R1 + (float)T * b_out[1];
  }
}

extern "C" void kernel_launch(void* const* d_in, const int* in_sizes, int n_in,
                              void* d_out, int out_size, void* d_ws, size_t ws_size,
                              hipStream_t stream) {
  const float* x    = (const float*)d_in[0];
  const float* Win  = (const float*)d_in[1];
  const float* bin  = (const float*)d_in[2];
  const float* lng  = (const float*)d_in[3];
  const float* lnb  = (const float*)d_in[4];
  const float* Wout = (const float*)d_in[5];
  const float* bout = (const float*)d_in[6];
  float* out = (float*)d_out;

  int B = out_size / 2;                 // 2048
  int T = in_sizes[0] / (B * 4);        // 512

  snn_mfma_kernel<<<dim3(B), dim3(256), 0, stream>>>(
      x, Win, bin, lng, lnb, Wout, bout, out, T);
}